// Round 3
// baseline (593.892 us; speedup 1.0000x reference)
//
#include <hip/hip_runtime.h>
#include <stdint.h>

#define BATCH 16
#define CDIM 64
#define NDIM 65536
#define EPSV 1e-6f

typedef __attribute__((ext_vector_type(8))) short bf16x8;
typedef __attribute__((ext_vector_type(4))) short bf16x4;
typedef __attribute__((ext_vector_type(4))) float f32x4;
typedef __attribute__((ext_vector_type(4))) uint32_t u32x4;
typedef __attribute__((ext_vector_type(2))) uint32_t u32x2;

static __device__ __forceinline__ uint32_t rne_u(float f) {
    uint32_t u = __builtin_bit_cast(uint32_t, f);
    return u + 0x7fffu + ((u >> 16) & 1u);
}
// low16 = bf16(a), high16 = bf16(b)  (RNE), single v_perm_b32 combine
static __device__ __forceinline__ uint32_t pk_rne(float a, float b) {
    return __builtin_amdgcn_perm(rne_u(a), rne_u(b), 0x03020706u);
}
static __device__ __forceinline__ float bf_lo(uint32_t u) {
    return __builtin_bit_cast(float, u << 16);
}
static __device__ __forceinline__ float bf_hi(uint32_t u) {
    return __builtin_bit_cast(float, u & 0xffff0000u);
}
static __device__ __forceinline__ float bf2f(uint32_t h) {
    return __builtin_bit_cast(float, h << 16);
}
static __device__ __forceinline__ uint32_t f2bf(float f) { return rne_u(f) >> 16; }

// ---------------- Kernel 1: Gram partials + tvec partials ----------------
// grid 1024 = 16 batches x 64 tiles; 4 chunks of 256 positions each.
// float4 global loads; raw tile held in registers (packed bf16) across the
// stats barrier -> no LDS rescale round-trip. tvec via extra MFMAs (g as
// replicated A-operand). LDS 38.4 KB -> 4 blocks/CU.
#define T1 256
#define P1 264
#define CHUNKS 4
#define NTILE1 64

__global__ __launch_bounds__(256, 4)
void gram_kernel(const float* __restrict__ x, float* __restrict__ pmat,
                 float* __restrict__ pt) {
    __shared__ __align__(16) short ldsU[CDIM][P1];      // 33792 B
    __shared__ __align__(16) short ldsGbf[T1];          // 512 B (g, bf16)
    __shared__ __align__(16) uint32_t red[4][T1];       // 4096 B (bf16 ss|cs)

    const int tid = threadIdx.x;
    const int b = blockIdx.x >> 6;
    const int tileIdx = blockIdx.x & 63;
    const int w = tid >> 6;
    const int l = tid & 63;        // position group: n = 4l..4l+3
    const int cq = l >> 4;
    const int cr = l & 15;

    f32x4 acc0 = {0.f, 0.f, 0.f, 0.f};
    f32x4 acc1 = acc0, acc2 = acc0, acc3 = acc0;
    f32x4 at0 = acc0, at1 = acc0, at2 = acc0, at3 = acc0;

    const float* xbase = x + (size_t)b * CDIM * NDIM + (size_t)(w * 16) * NDIM;

    for (int chunk = 0; chunk < CHUNKS; ++chunk) {
        const int n0 = tileIdx * (T1 * CHUNKS) + chunk * T1;
        const float* xb = xbase + n0 + 4 * l;
        f32x4 ssp = {0.f, 0.f, 0.f, 0.f};
        f32x4 csp = ssp;
        u32x2 raw[16];
        // phase A: 16 float4 loads (1 KB/wave-instr), stats partials, raw bf16 in regs
#pragma unroll
        for (int i = 0; i < 16; ++i) {
            f32x4 v = *(const f32x4*)(xb + (size_t)i * NDIM);
            ssp += v * v;
            csp += v;
            raw[i].x = pk_rne(v.x, v.y);
            raw[i].y = pk_rne(v.z, v.w);
        }
        u32x4 pk;
#pragma unroll
        for (int j = 0; j < 4; ++j) pk[j] = pk_rne(ssp[j], csp[j]);
        *(u32x4*)&red[w][4 * l] = pk;
        __syncthreads();
        // phase B: finalize stats for positions 4l..4l+3 (all 4 w-threads redundant)
        f32x4 ss = {0.f, 0.f, 0.f, 0.f};
        f32x4 cs = ss;
#pragma unroll
        for (int ww = 0; ww < 4; ++ww) {
            u32x4 q = *(const u32x4*)&red[ww][4 * l];
#pragma unroll
            for (int j = 0; j < 4; ++j) {
                ss[j] += bf_lo(q[j]);
                cs[j] += bf_hi(q[j]);
            }
        }
        f32x4 sq, gv;
#pragma unroll
        for (int j = 0; j < 4; ++j) {
            float inv = 1.f / (sqrtf(ss[j]) + EPSV);
            float s = sqrtf(inv);
            sq[j] = s;
            gv[j] = inv * s * cs[j];
        }
        if (w == 0) {
            u32x2 gw;
            gw.x = pk_rne(gv[0], gv[1]);
            gw.y = pk_rne(gv[2], gv[3]);
            *(u32x2*)&ldsGbf[4 * l] = gw;
        }
        // scale raw (in regs) and write u-tile
#pragma unroll
        for (int i = 0; i < 16; ++i) {
            float f0 = bf_lo(raw[i].x) * sq[0];
            float f1 = bf_hi(raw[i].x) * sq[1];
            float f2 = bf_lo(raw[i].y) * sq[2];
            float f3 = bf_hi(raw[i].y) * sq[3];
            u32x2 uw;
            uw.x = pk_rne(f0, f1);
            uw.y = pk_rne(f2, f3);
            *(u32x2*)&ldsU[w * 16 + i][4 * l] = uw;
        }
        __syncthreads();
        // MFMA: Gram rows [16w,16w+16) x 64 cols, plus tvec rows (g as A, replicated)
#pragma unroll
        for (int ks = 0; ks < 8; ++ks) {
            const int k0 = ks * 32 + cq * 8;
            bf16x8 afrag = *(const bf16x8*)&ldsU[w * 16 + cr][k0];
            bf16x8 gfrag = *(const bf16x8*)&ldsGbf[k0];
            bf16x8 b0 = *(const bf16x8*)&ldsU[cr][k0];
            bf16x8 b1 = *(const bf16x8*)&ldsU[16 + cr][k0];
            bf16x8 b2 = *(const bf16x8*)&ldsU[32 + cr][k0];
            bf16x8 b3 = *(const bf16x8*)&ldsU[48 + cr][k0];
            acc0 = __builtin_amdgcn_mfma_f32_16x16x32_bf16(afrag, b0, acc0, 0, 0, 0);
            acc1 = __builtin_amdgcn_mfma_f32_16x16x32_bf16(afrag, b1, acc1, 0, 0, 0);
            acc2 = __builtin_amdgcn_mfma_f32_16x16x32_bf16(afrag, b2, acc2, 0, 0, 0);
            acc3 = __builtin_amdgcn_mfma_f32_16x16x32_bf16(afrag, b3, acc3, 0, 0, 0);
            at0 = __builtin_amdgcn_mfma_f32_16x16x32_bf16(gfrag, b0, at0, 0, 0, 0);
            at1 = __builtin_amdgcn_mfma_f32_16x16x32_bf16(gfrag, b1, at1, 0, 0, 0);
            at2 = __builtin_amdgcn_mfma_f32_16x16x32_bf16(gfrag, b2, at2, 0, 0, 0);
            at3 = __builtin_amdgcn_mfma_f32_16x16x32_bf16(gfrag, b3, at3, 0, 0, 0);
        }
        __syncthreads();
    }
    // tvec partials: D-rows identical (A replicated); row 0 lives in lanes cq==0, reg 0
    if (tid < 16) {
        float* ptb = pt + (size_t)blockIdx.x * CDIM;
        ptb[tid] = at0[0];
        ptb[16 + tid] = at1[0];
        ptb[32 + tid] = at2[0];
        ptb[48 + tid] = at3[0];
    }
    // Gram partial: C/D layout col=lane&15, row=quad*4+reg
    float* pm = pmat + (size_t)blockIdx.x * CDIM * CDIM;
    const f32x4 accs[4] = {acc0, acc1, acc2, acc3};
#pragma unroll
    for (int mt = 0; mt < 4; ++mt) {
#pragma unroll
        for (int r = 0; r < 4; ++r) {
            const int row = w * 16 + cq * 4 + r;
            const int col = mt * 16 + cr;
            pm[row * CDIM + col] = accs[mt][r];
        }
    }
}

// ---------------- Kernel 1.5: reduce partials -> mat, tailor ----------------
__global__ __launch_bounds__(256, 4)
void reduce_kernel(const float* __restrict__ pmat, const float* __restrict__ pt,
                   float* __restrict__ mat, float* __restrict__ tl) {
    const int blk = blockIdx.x;
    const int tid = threadIdx.x;
    if (blk < 256) {
        const int b = blk >> 4;
        const int o = (blk & 15) * 256 + tid;
        float s = 0.f;
#pragma unroll 8
        for (int t = 0; t < NTILE1; ++t)
            s += pmat[((size_t)(b * NTILE1 + t)) * (CDIM * CDIM) + o];
        mat[b * CDIM * CDIM + o] = s;
    } else {
        const int idx = (blk - 256) * 256 + tid;
        const int b = idx >> 6;
        const int c = idx & 63;
        float s = 0.f;
#pragma unroll 8
        for (int t = 0; t < NTILE1; ++t)
            s += pt[(size_t)(b * NTILE1 + t) * CDIM + c];
        tl[idx] = 1.f / ((float)NDIM + s + EPSV);
    }
}

// ---------------- Kernel 2: matvec + fused epilogue ----------------
// A-frags (mat, 16 KB/batch, L2-hot) loaded straight from global -> no ldsM;
// LDS ~37 KB -> 4 blocks/CU. Per-p accumulators with fused per-p epilogue.
#define T2 256
#define P2 68

__global__ __launch_bounds__(256, 4)
void out_kernel(const float* __restrict__ x, const float* __restrict__ mat,
                const float* __restrict__ tl, const float* __restrict__ gamma,
                float* __restrict__ out) {
    __shared__ __align__(16) short ldsV[T2][P2];   // 34816 B
    __shared__ float ldsCS[T2];
    __shared__ float ldsIN[T2];
    __shared__ float ldsTL[CDIM];

    const int tid = threadIdx.x;
    const int bid = (int)(gridDim.x - 1 - blockIdx.x);
    const int b = bid >> 8;
    const int n0 = (bid & 255) * T2;
    const int w = tid >> 6;
    const int lane = tid & 63;
    const int cq = lane >> 4;
    const int cr = lane & 15;

    if (tid < CDIM) ldsTL[tid] = tl[b * CDIM + tid];

    // A-frags direct from global (independent of tile phase)
    const float* mb = mat + (size_t)b * CDIM * CDIM;
    bf16x8 afrag[4][2];
#pragma unroll
    for (int ct = 0; ct < 4; ++ct)
#pragma unroll
        for (int ks = 0; ks < 2; ++ks) {
            const float* ap = mb + (ct * 16 + cr) * CDIM + ks * 32 + cq * 8;
            f32x4 m0 = *(const f32x4*)ap;
            f32x4 m1 = *(const f32x4*)(ap + 4);
            u32x4 pkv;
            pkv.x = pk_rne(m0.x, m0.y);
            pkv.y = pk_rne(m0.z, m0.w);
            pkv.z = pk_rne(m1.x, m1.y);
            pkv.w = pk_rne(m1.z, m1.w);
            afrag[ct][ks] = __builtin_bit_cast(bf16x8, pkv);
        }

    // load x tile transposed [n][c]; thread owns position n0+tid; in-reg stats
    const float* xb = x + (size_t)b * CDIM * NDIM + n0 + tid;
    float ss = 0.f, cs = 0.f;
#pragma unroll 8
    for (int cp = 0; cp < 32; ++cp) {
        float v0 = xb[(size_t)(2 * cp) * NDIM];
        float v1 = xb[(size_t)(2 * cp + 1) * NDIM];
        ss += v0 * v0 + v1 * v1;
        cs += v0 + v1;
        *(uint32_t*)&ldsV[tid][2 * cp] = pk_rne(v0, v1);
    }
    ldsIN[tid] = 1.f / (sqrtf(ss) + EPSV);
    ldsCS[tid] = cs;
    __syncthreads();

    const float g = gamma[0];
    float* ob = out + (size_t)b * CDIM * NDIM + n0;

    // D(64 x 256) = M @ V; wave w handles p-tiles 4w..4w+3; fused epilogue per p
#pragma unroll
    for (int p = 0; p < 4; ++p) {
        const int n = (w * 4 + p) * 16 + cr;
        bf16x8 bfr[2];
#pragma unroll
        for (int ks = 0; ks < 2; ++ks) {
            const int k0 = ks * 32 + cq * 8;
            bf16x4 lo = *(const bf16x4*)&ldsV[n][k0];
            bf16x4 hi = *(const bf16x4*)&ldsV[n][k0 + 4];
            bfr[ks] = __builtin_shufflevector(lo, hi, 0, 1, 2, 3, 4, 5, 6, 7);
        }
        f32x4 acc[4];
#pragma unroll
        for (int ct = 0; ct < 4; ++ct) acc[ct] = (f32x4){0.f, 0.f, 0.f, 0.f};
#pragma unroll
        for (int ks = 0; ks < 2; ++ks)
#pragma unroll
            for (int ct = 0; ct < 4; ++ct)
                acc[ct] = __builtin_amdgcn_mfma_f32_16x16x32_bf16(
                    afrag[ct][ks], bfr[ks], acc[ct], 0, 0, 0);

        const float csn = ldsCS[n];
        const float invn = ldsIN[n];
#pragma unroll
        for (int ct = 0; ct < 4; ++ct) {
            const int c0 = ct * 16 + cq * 4;
            bf16x4 xv4 = *(const bf16x4*)&ldsV[n][c0];
#pragma unroll
            for (int r = 0; r < 4; ++r) {
                const int c = c0 + r;
                ob[(size_t)c * NDIM + n] =
                    bf2f((uint32_t)(uint16_t)xv4[r]) +
                    g * ldsTL[c] * (csn + invn * acc[ct][r]);
            }
        }
    }
}

extern "C" void kernel_launch(void* const* d_in, const int* in_sizes, int n_in,
                              void* d_out, int out_size, void* d_ws, size_t ws_size,
                              hipStream_t stream) {
    const float* x = (const float*)d_in[0];
    const float* gamma = (const float*)d_in[1];
    float* out = (float*)d_out;
    float* pmat = (float*)d_ws;                            // 1024 x 4096 f32
    float* pt = pmat + (size_t)1024 * CDIM * CDIM;         // 1024 x 64 f32
    float* mat = pt + (size_t)1024 * CDIM;                 // 16 x 4096 f32
    float* tl = mat + BATCH * CDIM * CDIM;                 // 16 x 64 f32
    hipLaunchKernelGGL(gram_kernel, dim3(BATCH * NTILE1), dim3(256), 0, stream,
                       x, pmat, pt);
    hipLaunchKernelGGL(reduce_kernel, dim3(260), dim3(256), 0, stream,
                       pmat, pt, mat, tl);
    hipLaunchKernelGGL(out_kernel, dim3(BATCH * 256), dim3(256), 0, stream,
                       x, mat, tl, gamma, out);
}